// Round 9
// baseline (648.511 us; speedup 1.0000x reference)
//
#include <hip/hip_runtime.h>

constexpr int TT = 512;    // timesteps
constexpr int BB = 256;    // batch
constexpr int HH = 128;    // hidden = embed
constexpr int VV = 32000;  // vocab

typedef _Float16 h2 __attribute__((ext_vector_type(2)));
typedef _Float16 f16x4 __attribute__((ext_vector_type(4)));
typedef _Float16 f16x8 __attribute__((ext_vector_type(8)));
typedef float f32x4 __attribute__((ext_vector_type(4)));

struct __align__(16) H2x4 { h2 a, b, c, d; };

__device__ __forceinline__ h2 pkrtz(float a, float b) {
  return __builtin_bit_cast(h2, __builtin_amdgcn_cvt_pkrtz(a, b));
}
__device__ __forceinline__ float fdot2(h2 a, h2 b, float c) {
  return __builtin_amdgcn_fdot2(a, b, c, false);
}
__device__ __forceinline__ float fsigmoid(float x) {
  return 1.f / (1.f + __expf(-x));
}
__device__ __forceinline__ float ftanh(float x) {
  return 1.f - 2.f / (__expf(2.f * x) + 1.f);
}

// One block per batch element (256 blocks = 256 CUs), 512 threads = 8 waves.
// Identical to R8 except __launch_bounds__(512, 1):
// at (512,2) the unified reg budget is 256/wave and the allocator splits it
// 128 arch + 128 acc, pushing the 128-reg weight array into AGPRs; v_dot2
// can't source AGPRs -> ~230 v_accvgpr_read copies per wave per step (the
// measured 2.4x VALU inflation, VGPR_Count pinned at 128 in R1/R5/R8).
// At (512,1) the budget is 512/wave; demand (~180) fits in arch VGPRs ->
// no copies. Achieved occupancy unchanged: 8-wave block = 2 waves/SIMD,
// 2 x ~190 regs < 512/SIMD pool.
__global__ __launch_bounds__(512, 1) void lstm_rec(
    const int* __restrict__ x, const float* __restrict__ emb,
    const float* __restrict__ Wi, const float* __restrict__ bi,
    const float* __restrict__ Wf, const float* __restrict__ bf,
    const float* __restrict__ Wc, const float* __restrict__ bc,
    const float* __restrict__ Wo, const float* __restrict__ bo,
    _Float16* __restrict__ hbf) {
  const int b = blockIdx.x;
  const int tid = threadIdx.x;
  const int w = tid >> 6;   // k-slice 0..7
  const int l = tid & 63;   // unit pair

  __shared__ int xrow[TT];
  __shared__ __align__(16) _Float16 comb[2][256];    // [buf][k] f16 (e|h)
  __shared__ __align__(16) _Float16 part[8][64][8];  // [slice][pair][8 gates]

  xrow[tid & (TT - 1)] = x[b * TT + (tid & (TT - 1))];

  // ---- weights: wfr[g][j][i] = {Wg[k0+2i][2l+j], Wg[k0+2i+1][2l+j]}, k0=32w
  // float2 loads are fully lane-coalesced (lane l -> cols 2l,2l+1).
  const float* Wp[4] = {Wi, Wf, Wc, Wo};
  h2 wfr[4][2][16];
#pragma unroll
  for (int g = 0; g < 4; ++g) {
    const float* Wg = Wp[g];
#pragma unroll
    for (int i = 0; i < 16; ++i) {
      const int k0 = 32 * w + 2 * i;
      const float2 r0 = *(const float2*)(Wg + (size_t)k0 * HH + 2 * l);
      const float2 r1 = *(const float2*)(Wg + (size_t)(k0 + 1) * HH + 2 * l);
      wfr[g][0][i] = h2{(_Float16)r0.x, (_Float16)r1.x};
      wfr[g][1][i] = h2{(_Float16)r0.y, (_Float16)r1.y};
    }
  }

  // reducer state (threads 0..127 = waves 0,1): unit u = tid
  const int u = tid;
  const bool red = (tid < 128);
  float bia = 0.f, bif_ = 0.f, bic = 0.f, bio = 0.f, cst = 0.f;
  if (red) { bia = bi[u]; bif_ = bf[u]; bic = bc[u]; bio = bo[u]; }

  __syncthreads();  // xrow visible

  // ---- init comb[0]: e_0 | h_0 = 0
  if (red) {
    const float e0 = emb[(size_t)xrow[0] * HH + u];
    comb[0][u] = (_Float16)e0;
    comb[0][128 + u] = (_Float16)0.f;
  }
  __syncthreads();

  const h2 LO = h2{(_Float16)1.f, (_Float16)0.f};
  const h2 HI = h2{(_Float16)0.f, (_Float16)1.f};

  int buf = 0;
  for (int t = 0; t < TT; ++t) {
    // reducers: issue e_{t+1} gather early (L3-resident emb; used in phase 2)
    float e_nf = 0.f;
    if (red) {
      const int tn = (t + 1 < TT) ? t + 1 : TT - 1;
      e_nf = emb[(size_t)xrow[tn] * HH + u];
    }

    // ---- phase 1: partial dots over own 32-k slice (all threads)
    h2 cc[16];
    {
      const _Float16* cp = &comb[buf][32 * w];
#pragma unroll
      for (int c = 0; c < 4; ++c) {
        const f16x8 v = *(const f16x8*)(cp + 8 * c);
        cc[4 * c + 0] = h2{v[0], v[1]};
        cc[4 * c + 1] = h2{v[2], v[3]};
        cc[4 * c + 2] = h2{v[4], v[5]};
        cc[4 * c + 3] = h2{v[6], v[7]};
      }
    }
    float a0[4], a1[4];  // 4 gates for unit 2l, 2l+1
#pragma unroll
    for (int g = 0; g < 4; ++g) {
      float s0 = 0.f, s1 = 0.f;
#pragma unroll
      for (int i = 0; i < 16; ++i) {
        s0 = fdot2(cc[i], wfr[g][0][i], s0);
        s1 = fdot2(cc[i], wfr[g][1][i], s1);
      }
      a0[g] = s0;
      a1[g] = s1;
    }
    {
      H2x4 q;
      q.a = pkrtz(a0[0], a0[1]);  // i,f of unit 2l
      q.b = pkrtz(a0[2], a0[3]);  // c,o of unit 2l
      q.c = pkrtz(a1[0], a1[1]);  // i,f of unit 2l+1
      q.d = pkrtz(a1[2], a1[3]);  // c,o of unit 2l+1
      *(H2x4*)(&part[w][l][0]) = q;
    }
    __syncthreads();  // partials visible

    // ---- phase 2: reduce + activate + state update (waves 0,1)
    if (red) {
      float ai = 0.f, af = 0.f, ac = 0.f, ao = 0.f;
      // unit u's (i,f,c,o) quad lives at f16 offset (u>>1)*8 + 4*(u&1) = 4u
      // within each slice's 512-f16 region: contiguous 8B/lane, conflict-free.
      const _Float16* pb = &part[0][0][0] + (size_t)u * 4;
#pragma unroll
      for (int s = 0; s < 8; ++s) {
        const f16x4 pp = *(const f16x4*)(pb + s * 512);
        const h2 pif = h2{pp[0], pp[1]};
        const h2 pco = h2{pp[2], pp[3]};
        ai = fdot2(pif, LO, ai);
        af = fdot2(pif, HI, af);
        ac = fdot2(pco, LO, ac);
        ao = fdot2(pco, HI, ao);
      }
      const float gi = fsigmoid(ai + bia);
      const float gf = fsigmoid(af + bif_);
      const float gc = ftanh(ac + bic);
      const float go = fsigmoid(ao + bio);
      cst = gf * cst + gi * gc;
      const float hv = go * ftanh(cst);
      comb[buf ^ 1][128 + u] = (_Float16)hv;
      comb[buf ^ 1][u] = (_Float16)e_nf;
      if (t == TT - 1) hbf[(size_t)b * HH + u] = (_Float16)hv;
    }
    __syncthreads();  // comb[buf^1] complete
    buf ^= 1;
  }
}

// Wout[k][v] fp32 -> Wt[v][k] fp16 (coalesced loads across lanes=v).
__global__ __launch_bounds__(256, 4) void wout_tr(const float* __restrict__ Wout,
                                                  _Float16* __restrict__ Wt) {
  const int v = blockIdx.x * 256 + threadIdx.x;
#pragma unroll 1
  for (int kc = 0; kc < 16; ++kc) {
    float f[8];
#pragma unroll
    for (int i = 0; i < 8; ++i) f[i] = Wout[(size_t)(kc * 8 + i) * VV + v];
    H2x4 q;
    q.a = pkrtz(f[0], f[1]);
    q.b = pkrtz(f[2], f[3]);
    q.c = pkrtz(f[4], f[5]);
    q.d = pkrtz(f[6], f[7]);
    *(H2x4*)(Wt + (size_t)v * HH + kc * 8) = q;
  }
}

// logits = h @ Wout + bout via f16 MFMA, register-only.
// Block: 4 waves; tile [64 bat x 128 v]; wave: [64 bat x 32 v].
__global__ __launch_bounds__(256, 4) void lstm_out(
    const _Float16* __restrict__ Wt, const _Float16* __restrict__ hbf,
    const float* __restrict__ bout, float* __restrict__ out) {
  const int tid = threadIdx.x;
  const int wv = tid >> 6;
  const int lane = tid & 63;
  const int vblk = blockIdx.x % 250;
  const int batblk = blockIdx.x / 250;
  const int n16 = lane & 15;
  const int quad = lane >> 4;
  const int vbase = vblk * 128 + wv * 32;
  const int batbase = batblk * 64;

  f32x4 acc[4][2] = {};
#pragma unroll
  for (int ks = 0; ks < 4; ++ks) {
    const int k = ks * 32 + quad * 8;
    f16x8 a[4], bf_[2];
#pragma unroll
    for (int mt = 0; mt < 4; ++mt)
      a[mt] = *(const f16x8*)(hbf + (size_t)(batbase + mt * 16 + n16) * HH + k);
#pragma unroll
    for (int vt = 0; vt < 2; ++vt)
      bf_[vt] = *(const f16x8*)(Wt + (size_t)(vbase + vt * 16 + n16) * HH + k);
#pragma unroll
    for (int mt = 0; mt < 4; ++mt)
#pragma unroll
      for (int vt = 0; vt < 2; ++vt)
        acc[mt][vt] = __builtin_amdgcn_mfma_f32_16x16x32_f16(a[mt], bf_[vt],
                                                             acc[mt][vt], 0, 0, 0);
  }
#pragma unroll
  for (int vt = 0; vt < 2; ++vt) {
    const int v = vbase + vt * 16 + n16;
    const float bv = bout[v];
#pragma unroll
    for (int mt = 0; mt < 4; ++mt) {
#pragma unroll
      for (int r = 0; r < 4; ++r) {
        const int bat = batbase + mt * 16 + quad * 4 + r;
        out[(size_t)bat * VV + v] = acc[mt][vt][r] + bv;
      }
    }
  }
}

extern "C" void kernel_launch(void* const* d_in, const int* in_sizes, int n_in,
                              void* d_out, int out_size, void* d_ws,
                              size_t ws_size, hipStream_t stream) {
  const int* x = (const int*)d_in[0];
  const float* emb = (const float*)d_in[1];
  const float* Wi = (const float*)d_in[2];
  const float* bi = (const float*)d_in[3];
  const float* Wf = (const float*)d_in[4];
  const float* bf = (const float*)d_in[5];
  const float* Wc = (const float*)d_in[6];
  const float* bc = (const float*)d_in[7];
  const float* Wo = (const float*)d_in[8];
  const float* bo = (const float*)d_in[9];
  const float* Wout = (const float*)d_in[10];
  const float* bout = (const float*)d_in[11];
  float* out = (float*)d_out;

  _Float16* Wt = (_Float16*)d_ws;        // 32000*128 f16 = 8.192 MB
  _Float16* hbf = Wt + (size_t)VV * HH;  // 256*128 f16 = 64 KB

  wout_tr<<<VV / 256, 256, 0, stream>>>(Wout, Wt);
  lstm_rec<<<BB, 512, 0, stream>>>(x, emb, Wi, bi, Wf, bf, Wc, bc, Wo, bo, hbf);
  lstm_out<<<(VV / 128) * (BB / 64), 256, 0, stream>>>(Wt, hbf, bout, out);
}